// Round 1
// baseline (3405.843 us; speedup 1.0000x reference)
//
#include <hip/hip_runtime.h>
#include <math.h>

#define B_   2
#define S_   2048
#define H_   2048
#define NH_  16
#define HD_  128
#define M_   (B_ * S_)    // 4096 rows total
#define TH_  (3 * H_)     // 6144 qkv cols

// ---------------------------------------------------------------------------
// GEMM (TN): C[M][N] = A[M][K] @ Bm[N][K]^T   (both operands K-major, fp32)
// Tile 128x128, BK=16, 256 threads, 8x8 micro-tile with split +-64 groups.
// QK_EPI=1: for n-tiles 0..31 (q heads 0..15, k heads 0..15) fuse
//           RoPE + RMSNorm into the epilogue. Tile == one head (BN=128=HD).
// ---------------------------------------------------------------------------
template <int QK_EPI>
__global__ __launch_bounds__(256, 2) void gemm_tn(
    const float* __restrict__ A, const float* __restrict__ Bm,
    float* __restrict__ C, int Mdim, int Ndim, int Kdim,
    const float* __restrict__ qln, const float* __restrict__ kln,
    const int* __restrict__ pos)
{
  __shared__ float As[16][132];
  __shared__ float Bs[16][132];

  const int t  = threadIdx.x;
  const int tx = t & 15;        // 0..15 -> col groups
  const int ty = t >> 4;        // 0..15 -> row groups
  const int m0 = blockIdx.y * 128;
  const int n0 = blockIdx.x * 128;

  // cooperative-load indices: 64 rows x 16 k each half
  const int lr = t >> 2;            // 0..63
  const int lk = (t & 3) * 4;       // 0,4,8,12

  float acc[8][8];
#pragma unroll
  for (int i = 0; i < 8; ++i)
#pragma unroll
    for (int j = 0; j < 8; ++j) acc[i][j] = 0.f;

  const float* Ap = A  + (size_t)(m0 + lr) * Kdim + lk;
  const float* Bp = Bm + (size_t)(n0 + lr) * Kdim + lk;
  const size_t halfA = (size_t)64 * Kdim;

  for (int k0 = 0; k0 < Kdim; k0 += 16) {
    const float4 a0 = *(const float4*)(Ap + k0);
    const float4 a1 = *(const float4*)(Ap + halfA + k0);
    const float4 b0 = *(const float4*)(Bp + k0);
    const float4 b1 = *(const float4*)(Bp + halfA + k0);
    __syncthreads();   // previous iteration's compute done
    As[lk+0][lr] = a0.x; As[lk+1][lr] = a0.y; As[lk+2][lr] = a0.z; As[lk+3][lr] = a0.w;
    As[lk+0][64+lr] = a1.x; As[lk+1][64+lr] = a1.y; As[lk+2][64+lr] = a1.z; As[lk+3][64+lr] = a1.w;
    Bs[lk+0][lr] = b0.x; Bs[lk+1][lr] = b0.y; Bs[lk+2][lr] = b0.z; Bs[lk+3][lr] = b0.w;
    Bs[lk+0][64+lr] = b1.x; Bs[lk+1][64+lr] = b1.y; Bs[lk+2][64+lr] = b1.z; Bs[lk+3][64+lr] = b1.w;
    __syncthreads();
#pragma unroll
    for (int kk = 0; kk < 16; ++kk) {
      const float4 av0 = *(const float4*)&As[kk][ty * 4];
      const float4 av1 = *(const float4*)&As[kk][64 + ty * 4];
      const float4 bv0 = *(const float4*)&Bs[kk][tx * 4];
      const float4 bv1 = *(const float4*)&Bs[kk][64 + tx * 4];
      const float ar[8] = {av0.x, av0.y, av0.z, av0.w, av1.x, av1.y, av1.z, av1.w};
      const float br[8] = {bv0.x, bv0.y, bv0.z, bv0.w, bv1.x, bv1.y, bv1.z, bv1.w};
#pragma unroll
      for (int i = 0; i < 8; ++i)
#pragma unroll
        for (int j = 0; j < 8; ++j) acc[i][j] = fmaf(ar[i], br[j], acc[i][j]);
    }
  }

  // ---- epilogue ----
  if (QK_EPI && blockIdx.x < 32) {
    // this 128-col tile is exactly one q-head (bx<16) or k-head (16..31)
    const float* lnw = (blockIdx.x < 16) ? qln : kln;
    float invf[4], wl[8];
#pragma unroll
    for (int j = 0; j < 4; ++j) {
      const int d = tx * 4 + j;                       // freq index 0..63
      invf[j]  = powf(10000.0f, -(float)d * (1.0f / 64.0f));
      wl[j]    = lnw[d];
      wl[j+4]  = lnw[64 + d];
    }
#pragma unroll
    for (int i = 0; i < 8; ++i) {
      const int r = (i < 4) ? (ty * 4 + i) : (64 + ty * 4 + i - 4);
      const int m = m0 + r;
      const float p = (float)pos[m];
      float y[8];
#pragma unroll
      for (int j = 0; j < 4; ++j) {
        float sn, cs;
        sincosf(p * invf[j], &sn, &cs);
        const float x1 = acc[i][j], x2 = acc[i][j + 4];
        y[j]     = fmaf(x1, cs, -(x2 * sn));   // x1*cos - x2*sin
        y[j + 4] = fmaf(x2, cs,  (x1 * sn));   // x2*cos + x1*sin
      }
      float ss = 0.f;
#pragma unroll
      for (int j = 0; j < 8; ++j) ss += y[j] * y[j];
      ss += __shfl_xor(ss, 1, 16);
      ss += __shfl_xor(ss, 2, 16);
      ss += __shfl_xor(ss, 4, 16);
      ss += __shfl_xor(ss, 8, 16);     // sum over the 128 cols of this head
      const float sc = rsqrtf(ss * (1.0f / 128.0f) + 1e-6f);
      const float4 o0 = make_float4(y[0]*wl[0]*sc, y[1]*wl[1]*sc, y[2]*wl[2]*sc, y[3]*wl[3]*sc);
      const float4 o1 = make_float4(y[4]*wl[4]*sc, y[5]*wl[5]*sc, y[6]*wl[6]*sc, y[7]*wl[7]*sc);
      *(float4*)(C + (size_t)m * Ndim + n0 + tx * 4)      = o0;
      *(float4*)(C + (size_t)m * Ndim + n0 + 64 + tx * 4) = o1;
    }
  } else {
#pragma unroll
    for (int i = 0; i < 8; ++i) {
      const int r = (i < 4) ? (ty * 4 + i) : (64 + ty * 4 + i - 4);
      const int m = m0 + r;
      const float4 o0 = make_float4(acc[i][0], acc[i][1], acc[i][2], acc[i][3]);
      const float4 o1 = make_float4(acc[i][4], acc[i][5], acc[i][6], acc[i][7]);
      *(float4*)(C + (size_t)m * Ndim + n0 + tx * 4)      = o0;
      *(float4*)(C + (size_t)m * Ndim + n0 + 64 + tx * 4) = o1;
    }
  }
}

// ---------------------------------------------------------------------------
// Flash attention (non-causal, fp32 vector FMA).
// Block = 256 threads = one (b, h, 128-row Q tile). KV tiles of 64 rows.
// K and V time-share one LDS buffer. P staged through LDS for the PV GEMM.
// Thread (ty,tx): S rows R(i)=ty+16i (i<8), S cols tx*4+j (j<4);
//                 O rows R(i), O cols tx*4+{0..3} and 64+tx*4+{0..3}.
// ---------------------------------------------------------------------------
__global__ __launch_bounds__(256, 1) void attn_kernel(
    const float* __restrict__ qkv, float* __restrict__ attn)
{
  __shared__ float Qs[128][132];
  __shared__ float KVs[64][132];
  __shared__ float Ps[128][64];

  const int t  = threadIdx.x;
  const int tx = t & 15;
  const int ty = t >> 4;
  const int q0 = blockIdx.x * 128;
  const int h  = blockIdx.y;
  const int b  = blockIdx.z;

  const float* qbase = qkv + (size_t)b * S_ * TH_ + (size_t)h * HD_;
  const float* kbase = qbase + H_;
  const float* vbase = qbase + 2 * H_;

  // load Q tile (128 x 128): 2 threads per row, 64 floats each
  {
    const int r  = t >> 1;
    const int c0 = (t & 1) * 64;
    const float* src = qbase + (size_t)(q0 + r) * TH_ + c0;
#pragma unroll
    for (int u = 0; u < 16; ++u)
      *(float4*)&Qs[r][c0 + u * 4] = *(const float4*)(src + u * 4);
  }

  float m_i[8], l_i[8], O[8][8];
#pragma unroll
  for (int i = 0; i < 8; ++i) {
    m_i[i] = -3.0e38f;
    l_i[i] = 0.f;
#pragma unroll
    for (int c = 0; c < 8; ++c) O[i][c] = 0.f;
  }
  __syncthreads();

  const int lr = t >> 2;           // 0..63
  const int lc = (t & 3) * 32;     // 0,32,64,96
  const float scale = 0.08838834764831845f;  // 1/sqrt(128)

  for (int j0 = 0; j0 < S_; j0 += 64) {
    // ---- stage K tile (64x128) ----
    float4 kreg[8];
    {
      const float* src = kbase + (size_t)(j0 + lr) * TH_ + lc;
#pragma unroll
      for (int u = 0; u < 8; ++u) kreg[u] = *(const float4*)(src + u * 4);
    }
    __syncthreads();               // prev PV reads of KVs done
#pragma unroll
    for (int u = 0; u < 8; ++u) *(float4*)&KVs[lr][lc + u * 4] = kreg[u];
    __syncthreads();

    // ---- S = Q @ K^T (128x64), scaled ----
    float Sv[8][4];
#pragma unroll
    for (int i = 0; i < 8; ++i)
#pragma unroll
      for (int j = 0; j < 4; ++j) Sv[i][j] = 0.f;

    for (int d = 0; d < 128; d += 4) {
      float4 qv[8], kv[4];
#pragma unroll
      for (int i = 0; i < 8; ++i) qv[i] = *(const float4*)&Qs[ty + 16 * i][d];
#pragma unroll
      for (int j = 0; j < 4; ++j) kv[j] = *(const float4*)&KVs[tx * 4 + j][d];
#pragma unroll
      for (int i = 0; i < 8; ++i)
#pragma unroll
        for (int j = 0; j < 4; ++j)
          Sv[i][j] += qv[i].x * kv[j].x + qv[i].y * kv[j].y +
                      qv[i].z * kv[j].z + qv[i].w * kv[j].w;
    }

    // ---- online softmax over this 64-col slab ----
#pragma unroll
    for (int i = 0; i < 8; ++i) {
      float mx = fmaxf(fmaxf(Sv[i][0], Sv[i][1]), fmaxf(Sv[i][2], Sv[i][3])) * 1.f;
      mx = fmaxf(Sv[i][0] * scale, fmaxf(Sv[i][1] * scale,
           fmaxf(Sv[i][2] * scale, Sv[i][3] * scale)));
      mx = fmaxf(mx, __shfl_xor(mx, 1, 16));
      mx = fmaxf(mx, __shfl_xor(mx, 2, 16));
      mx = fmaxf(mx, __shfl_xor(mx, 4, 16));
      mx = fmaxf(mx, __shfl_xor(mx, 8, 16));
      const float mnew = fmaxf(m_i[i], mx);
      const float alpha = __expf(m_i[i] - mnew);
      m_i[i] = mnew;
      l_i[i] *= alpha;
#pragma unroll
      for (int c = 0; c < 8; ++c) O[i][c] *= alpha;
      float ps = 0.f;
#pragma unroll
      for (int j = 0; j < 4; ++j) {
        const float p = __expf(Sv[i][j] * scale - mnew);
        Sv[i][j] = p;
        ps += p;
      }
      ps += __shfl_xor(ps, 1, 16);
      ps += __shfl_xor(ps, 2, 16);
      ps += __shfl_xor(ps, 4, 16);
      ps += __shfl_xor(ps, 8, 16);
      l_i[i] += ps;
      *(float4*)&Ps[ty + 16 * i][tx * 4] =
          make_float4(Sv[i][0], Sv[i][1], Sv[i][2], Sv[i][3]);
    }

    // ---- stage V tile into the same buffer ----
    float4 vreg[8];
    {
      const float* src = vbase + (size_t)(j0 + lr) * TH_ + lc;
#pragma unroll
      for (int u = 0; u < 8; ++u) vreg[u] = *(const float4*)(src + u * 4);
    }
    __syncthreads();               // S-phase reads of K + P writes done
#pragma unroll
    for (int u = 0; u < 8; ++u) *(float4*)&KVs[lr][lc + u * 4] = vreg[u];
    __syncthreads();

    // ---- O += P @ V ----
    for (int j = 0; j < 64; j += 4) {
      float4 pv[8], va[4], vb[4];
#pragma unroll
      for (int i = 0; i < 8; ++i) pv[i] = *(const float4*)&Ps[ty + 16 * i][j];
#pragma unroll
      for (int jj = 0; jj < 4; ++jj) {
        va[jj] = *(const float4*)&KVs[j + jj][tx * 4];
        vb[jj] = *(const float4*)&KVs[j + jj][64 + tx * 4];
      }
#pragma unroll
      for (int i = 0; i < 8; ++i) {
        const float pw[4] = {pv[i].x, pv[i].y, pv[i].z, pv[i].w};
#pragma unroll
        for (int jj = 0; jj < 4; ++jj) {
          O[i][0] = fmaf(pw[jj], va[jj].x, O[i][0]);
          O[i][1] = fmaf(pw[jj], va[jj].y, O[i][1]);
          O[i][2] = fmaf(pw[jj], va[jj].z, O[i][2]);
          O[i][3] = fmaf(pw[jj], va[jj].w, O[i][3]);
          O[i][4] = fmaf(pw[jj], vb[jj].x, O[i][4]);
          O[i][5] = fmaf(pw[jj], vb[jj].y, O[i][5]);
          O[i][6] = fmaf(pw[jj], vb[jj].z, O[i][6]);
          O[i][7] = fmaf(pw[jj], vb[jj].w, O[i][7]);
        }
      }
    }
  }

  // ---- epilogue: normalize and write attn[b,s,h*128+d] ----
#pragma unroll
  for (int i = 0; i < 8; ++i) {
    const int s = q0 + ty + 16 * i;
    const float inv = 1.0f / l_i[i];
    float* dst = attn + (size_t)(b * S_ + s) * H_ + h * HD_;
    const float4 o0 = make_float4(O[i][0]*inv, O[i][1]*inv, O[i][2]*inv, O[i][3]*inv);
    const float4 o1 = make_float4(O[i][4]*inv, O[i][5]*inv, O[i][6]*inv, O[i][7]*inv);
    *(float4*)(dst + tx * 4)      = o0;
    *(float4*)(dst + 64 + tx * 4) = o1;
  }
}

// ---------------------------------------------------------------------------
extern "C" void kernel_launch(void* const* d_in, const int* in_sizes, int n_in,
                              void* d_out, int out_size, void* d_ws, size_t ws_size,
                              hipStream_t stream)
{
  const float* hs   = (const float*)d_in[0];   // (B,S,H) f32
  const float* wqkv = (const float*)d_in[1];   // (3H,H)  f32
  const float* wo   = (const float*)d_in[2];   // (H,H)   f32
  const float* qln  = (const float*)d_in[3];   // (128)   f32
  const float* kln  = (const float*)d_in[4];   // (128)   f32
  const int*   pos  = (const int*)d_in[5];     // (B,S)   int32

  float* qkv  = (float*)d_ws;                      // M_ x 6144
  float* attn = qkv + (size_t)M_ * TH_;            // M_ x 2048
  float* out  = (float*)d_out;                     // M_ x 2048

  // QKV projection + fused RoPE + RMSNorm on q,k
  gemm_tn<1><<<dim3(TH_ / 128, M_ / 128), 256, 0, stream>>>(
      hs, wqkv, qkv, M_, TH_, H_, qln, kln, pos);

  // flash attention
  attn_kernel<<<dim3(S_ / 128, NH_, B_), 256, 0, stream>>>(qkv, attn);

  // output projection
  gemm_tn<0><<<dim3(H_ / 128, M_ / 128), 256, 0, stream>>>(
      attn, wo, out, M_, H_, H_, nullptr, nullptr, nullptr);
}

// Round 7
// 458.361 us; speedup vs baseline: 7.4305x; 7.4305x over previous
//
#include <hip/hip_runtime.h>
#include <math.h>

#define S_   2048
#define H_   2048
#define NH_  16
#define HD_  128
#define M_   4096
#define TH_  6144

typedef __attribute__((ext_vector_type(8))) short bf16x8;
typedef __attribute__((ext_vector_type(4))) float f32x4;

__device__ __forceinline__ ushort f2bf(float x) {
  unsigned u = __float_as_uint(x);
  u = (u + 0x7FFFu + ((u >> 16) & 1u)) >> 16;
  return (ushort)u;
}

__device__ __forceinline__ void gll16(const void* g, void* l) {
  __builtin_amdgcn_global_load_lds(
      (const __attribute__((address_space(1))) void*)g,
      (__attribute__((address_space(3))) void*)l, 16, 0, 0);
}

// ---------------------------------------------------------------------------
__global__ void cvt_kernel(const float* __restrict__ src,
                           ushort* __restrict__ dst, int n4) {
  int i = blockIdx.x * blockDim.x + threadIdx.x;
  if (i < n4) {
    float4 v = ((const float4*)src)[i];
    ushort4 o;
    o.x = f2bf(v.x); o.y = f2bf(v.y); o.z = f2bf(v.z); o.w = f2bf(v.w);
    ((ushort4*)dst)[i] = o;
  }
}

// cos/sin tables: ct/st[m*64 + d], d = frequency index 0..63
__global__ void rope_tab(const int* __restrict__ pos,
                         float* __restrict__ ct, float* __restrict__ st) {
  int idx = blockIdx.x * blockDim.x + threadIdx.x;   // < 4096*64
  int m = idx >> 6, d = idx & 63;
  // inv_freq = 10000^(-d/64) = exp2(-d * log2(10000)/64)
  float invf = exp2f(-(float)d * 0.20762050593046020f);
  float ang = (float)pos[m] * invf;
  float s, c;
  sincosf(ang, &s, &c);
  ct[idx] = c;
  st[idx] = s;
}

// ---------------------------------------------------------------------------
// C[M][N] = A[M][K] * Bm[N][K]^T, bf16 inputs, fp32 accum (m97 structure).
// 256 thr = 4 waves; tile 128x128, BK=32; wave w owns rows [32w,32w+32) x all
// 128 cols (2 m-frags x 8 n-frags of 16x16x32 MFMA).
// EPI=0: plain f32 store to C.
// EPI=1: qkv fusion. blockIdx.x>>4: 0=q,1=k (RoPE+RMSNorm -> bf16 [b,h,s,d]),
//        2=v (bf16 transposed store Vt[b,h,d,s]).
// ---------------------------------------------------------------------------
template <int EPI>
__global__ __launch_bounds__(256, 2) void gemm_bt(
    const ushort* __restrict__ A, const ushort* __restrict__ Bm,
    float* __restrict__ C, int Ndim, int Kdim,
    const float* __restrict__ qln, const float* __restrict__ kln,
    const float* __restrict__ ct, const float* __restrict__ st,
    ushort* __restrict__ qbuf, ushort* __restrict__ kbuf,
    ushort* __restrict__ vt)
{
  __shared__ ushort As[128 * 32];
  __shared__ ushort Bs[128 * 32];
  const int t = threadIdx.x, l = t & 63, w = t >> 6;
  const int q4 = l >> 4, c0 = l & 15;
  const int m0 = blockIdx.y * 128, n0 = blockIdx.x * 128;

  // staging: wave w loads A/B rows [32w,32w+32), 1KB chunks of 16 rows
  const ushort* ga0 = A  + (size_t)(m0 + 32 * w + (l >> 2)) * Kdim + (l & 3) * 8;
  const ushort* ga1 = ga0 + (size_t)16 * Kdim;
  const ushort* gb0 = Bm + (size_t)(n0 + 32 * w + (l >> 2)) * Kdim + (l & 3) * 8;
  const ushort* gb1 = gb0 + (size_t)16 * Kdim;
  ushort* lA0 = As + (32 * w) * 32;
  ushort* lA1 = As + (32 * w + 16) * 32;
  ushort* lB0 = Bs + (32 * w) * 32;
  ushort* lB1 = Bs + (32 * w + 16) * 32;

  f32x4 acc[2][8];
#pragma unroll
  for (int i = 0; i < 2; ++i)
#pragma unroll
    for (int j = 0; j < 8; ++j) acc[i][j] = (f32x4){0.f, 0.f, 0.f, 0.f};

  for (int k0 = 0; k0 < Kdim; k0 += 32) {
    gll16(ga0 + k0, lA0);
    gll16(ga1 + k0, lA1);
    gll16(gb0 + k0, lB0);
    gll16(gb1 + k0, lB1);
    __syncthreads();   // loads complete (vmcnt drain at barrier)
    bf16x8 af[2], bfr[8];
#pragma unroll
    for (int i = 0; i < 2; ++i)
      af[i] = *(const bf16x8*)(As + (32 * w + 16 * i + c0) * 32 + q4 * 8);
#pragma unroll
    for (int j = 0; j < 8; ++j)
      bfr[j] = *(const bf16x8*)(Bs + (16 * j + c0) * 32 + q4 * 8);
#pragma unroll
    for (int i = 0; i < 2; ++i)
#pragma unroll
      for (int j = 0; j < 8; ++j)
        acc[i][j] = __builtin_amdgcn_mfma_f32_16x16x32_bf16(
            af[i], bfr[j], acc[i][j], 0, 0, 0);
    __syncthreads();   // frag reads done before next stage overwrites
  }

  if (EPI == 0) {
#pragma unroll
    for (int i = 0; i < 2; ++i)
#pragma unroll
      for (int j = 0; j < 8; ++j) {
        float* cp = C + (size_t)(m0 + 32 * w + 16 * i + q4 * 4) * Ndim
                      + n0 + 16 * j + c0;
#pragma unroll
        for (int r = 0; r < 4; ++r) cp[(size_t)r * Ndim] = acc[i][j][r];
      }
  } else {
    const int seg = blockIdx.x >> 4;   // 0=q, 1=k, 2=v (tile == one head)
    const int h = blockIdx.x & 15;
    if (seg < 2) {
      const float* lnw = (seg == 0) ? qln : kln;
      ushort* obuf = (seg == 0) ? qbuf : kbuf;
      float wl[8];
#pragma unroll
      for (int j = 0; j < 8; ++j) wl[j] = lnw[16 * j + c0];
#pragma unroll
      for (int i = 0; i < 2; ++i)
#pragma unroll
        for (int r = 0; r < 4; ++r) {
          const int m = m0 + 32 * w + 16 * i + q4 * 4 + r;
          const int b = m >> 11, s = m & 2047;
          float y[8], ss = 0.f;
#pragma unroll
          for (int j = 0; j < 4; ++j) {
            const int d = 16 * j + c0;              // freq index 0..63
            const float cs = ct[m * 64 + d], sn = st[m * 64 + d];
            const float x1 = acc[i][j][r], x2 = acc[i][j + 4][r];
            y[j]     = x1 * cs - x2 * sn;
            y[j + 4] = x2 * cs + x1 * sn;
          }
#pragma unroll
          for (int j = 0; j < 8; ++j) ss += y[j] * y[j];
          ss += __shfl_xor(ss, 1, 16);
          ss += __shfl_xor(ss, 2, 16);
          ss += __shfl_xor(ss, 4, 16);
          ss += __shfl_xor(ss, 8, 16);              // full 128-col row sum
          const float sc = rsqrtf(ss * (1.f / 128.f) + 1e-6f);
          ushort* dst = obuf + ((size_t)(b * NH_ + h) * S_ + s) * HD_;
#pragma unroll
          for (int j = 0; j < 8; ++j) dst[16 * j + c0] = f2bf(y[j] * wl[j] * sc);
        }
    } else {
      // V: transposed store Vt[b][h][d][s]
      const int b = m0 >> 11;
      const int s0 = (m0 & 2047) + 32 * w + q4 * 4;
#pragma unroll
      for (int i = 0; i < 2; ++i)
#pragma unroll
        for (int j = 0; j < 8; ++j) {
          const int d = 16 * j + c0;
          const int s = s0 + 16 * i;
          ushort4 o;
          o.x = f2bf(acc[i][j][0]); o.y = f2bf(acc[i][j][1]);
          o.z = f2bf(acc[i][j][2]); o.w = f2bf(acc[i][j][3]);
          *(ushort4*)(vt + ((size_t)(b * NH_ + h) * HD_ + d) * S_ + s) = o;
        }
    }
  }
}

// ---------------------------------------------------------------------------
// Flash attention, bf16 MFMA. Block = 256 thr = 4 waves = 128 q-rows.
// Wave w: q rows [q0+32w, +32). Q in registers. KV tiles of 64 staged into
// XOR-swizzled LDS via pre-swizzled global_load_lds source (G4 fix).
// P goes through swizzled LDS (bf16) for the PV A-operand.
// ---------------------------------------------------------------------------
__global__ __launch_bounds__(256, 2) void attn_mfma(
    const ushort* __restrict__ qb, const ushort* __restrict__ kb,
    const ushort* __restrict__ vtb, ushort* __restrict__ ob)
{
  __shared__ ushort Ks[64 * 128];   // [kv][d], 16B slot s phys = s^(row&7)
  __shared__ ushort Vs[128 * 64];   // [d][kv], same swizzle
  __shared__ ushort Ps[128 * 64];   // [q][kv], same swizzle
  const int t = threadIdx.x, l = t & 63, w = t >> 6;
  const int q4 = l >> 4, c0 = l & 15;
  const int q0 = blockIdx.x * 128, h = blockIdx.y, b = blockIdx.z;
  const ushort* qh = qb + (size_t)(b * NH_ + h) * S_ * HD_;
  const ushort* kh = kb + (size_t)(b * NH_ + h) * S_ * HD_;
  const ushort* vh = vtb + (size_t)(b * NH_ + h) * HD_ * S_;

  // Q fragments in registers: rows 32w+16i+c0, k-chunk kc (8 elems each)
  bf16x8 qf[2][4];
#pragma unroll
  for (int i = 0; i < 2; ++i)
#pragma unroll
    for (int kc = 0; kc < 4; ++kc)
      qf[i][kc] = *(const bf16x8*)(qh + (size_t)(q0 + 32 * w + 16 * i + c0) * HD_
                                   + kc * 32 + q4 * 8);

  f32x4 Of[2][8];
#pragma unroll
  for (int i = 0; i < 2; ++i)
#pragma unroll
    for (int j = 0; j < 8; ++j) Of[i][j] = (f32x4){0.f, 0.f, 0.f, 0.f};
  float mI[8], lI[8];
#pragma unroll
  for (int i = 0; i < 8; ++i) { mI[i] = -3.0e38f; lI[i] = 0.f; }

  const float scale = 0.08838834764831843f;   // 1/sqrt(128)

  for (int kv0 = 0; kv0 < S_; kv0 += 64) {
    __syncthreads();   // prior iteration's LDS reads complete
#pragma unroll
    for (int j2 = 0; j2 < 4; ++j2) {
      {  // K: chunk = 4 rows x 256B; wave w covers rows [16w,16w+16)
        const int rowK = 16 * w + 4 * j2 + q4;
        gll16(kh + (size_t)(kv0 + rowK) * HD_ + (c0 ^ (rowK & 7)) * 8,
              Ks + (16 * w + 4 * j2) * 128);
      }
      {  // V: chunk = 8 rows x 128B; wave w covers d-rows [32w,32w+32)
        const int rowV = 32 * w + 8 * j2 + (l >> 3);
        gll16(vh + (size_t)rowV * S_ + kv0 + (((l & 7) ^ (rowV & 7)) * 8),
              Vs + (32 * w + 8 * j2) * 64);
      }
    }
    __syncthreads();   // staged tiles visible

    // ---- S = Q K^T : 2x4 frags per wave ----
    f32x4 Sv[2][4];
#pragma unroll
    for (int i = 0; i < 2; ++i)
#pragma unroll
      for (int j = 0; j < 4; ++j) Sv[i][j] = (f32x4){0.f, 0.f, 0.f, 0.f};
#pragma unroll
    for (int kc = 0; kc < 4; ++kc) {
      bf16x8 kf[4];
#pragma unroll
      for (int j = 0; j < 4; ++j) {
        const int row = 16 * j + c0;
        kf[j] = *(const bf16x8*)(Ks + row * 128 + (((kc * 4 + q4) ^ (row & 7)) * 8));
      }
#pragma unroll
      for (int i = 0; i < 2; ++i)
#pragma unroll
        for (int j = 0; j < 4; ++j)
          Sv[i][j] = __builtin_amdgcn_mfma_f32_16x16x32_bf16(
              qf[i][kc], kf[j], Sv[i][j], 0, 0, 0);
    }

    // ---- online softmax; P -> swizzled LDS (bf16) ----
#pragma unroll
    for (int i = 0; i < 2; ++i)
#pragma unroll
      for (int r = 0; r < 4; ++r) {
        const int idx = i * 4 + r;
        float s0 = Sv[i][0][r] * scale, s1 = Sv[i][1][r] * scale;
        float s2 = Sv[i][2][r] * scale, s3 = Sv[i][3][r] * scale;
        float mx = fmaxf(fmaxf(s0, s1), fmaxf(s2, s3));
        mx = fmaxf(mx, __shfl_xor(mx, 1, 16));
        mx = fmaxf(mx, __shfl_xor(mx, 2, 16));
        mx = fmaxf(mx, __shfl_xor(mx, 4, 16));
        mx = fmaxf(mx, __shfl_xor(mx, 8, 16));
        const float mnew = fmaxf(mI[idx], mx);
        const float alpha = __expf(mI[idx] - mnew);
        mI[idx] = mnew;
        lI[idx] *= alpha;
#pragma unroll
        for (int jd = 0; jd < 8; ++jd) Of[i][jd][r] *= alpha;
        const float p0 = __expf(s0 - mnew), p1 = __expf(s1 - mnew);
        const float p2 = __expf(s2 - mnew), p3 = __expf(s3 - mnew);
        float ps = p0 + p1 + p2 + p3;
        ps += __shfl_xor(ps, 1, 16);
        ps += __shfl_xor(ps, 2, 16);
        ps += __shfl_xor(ps, 4, 16);
        ps += __shfl_xor(ps, 8, 16);
        lI[idx] += ps;
        const int qrow = 32 * w + 16 * i + q4 * 4 + r;
        const int x = qrow & 7, cb = c0 & 7, ch = c0 >> 3;
        Ps[qrow * 64 + ((0 + ch) ^ x) * 8 + cb] = f2bf(p0);  // col 16*0+c0
        Ps[qrow * 64 + ((2 + ch) ^ x) * 8 + cb] = f2bf(p1);  // col 16*1+c0
        Ps[qrow * 64 + ((4 + ch) ^ x) * 8 + cb] = f2bf(p2);  // col 16*2+c0
        Ps[qrow * 64 + ((6 + ch) ^ x) * 8 + cb] = f2bf(p3);  // col 16*3+c0
      }

    // ---- O += P V  (Ps written & read by the same wave; DS in-order) ----
#pragma unroll
    for (int kc2 = 0; kc2 < 2; ++kc2) {
      bf16x8 pa[2];
#pragma unroll
      for (int i = 0; i < 2; ++i) {
        const int row = 32 * w + 16 * i + c0;
        pa[i] = *(const bf16x8*)(Ps + row * 64 + (((kc2 * 4 + q4) ^ (row & 7)) * 8));
      }
#pragma unroll
      for (int jd = 0; jd < 8; ++jd) {
        const int row = 16 * jd + c0;
        const bf16x8 vf =
            *(const bf16x8*)(Vs + row * 64 + (((kc2 * 4 + q4) ^ (row & 7)) * 8));
#pragma unroll
        for (int i = 0; i < 2; ++i)
          Of[i][jd] = __builtin_amdgcn_mfma_f32_16x16x32_bf16(
              pa[i], vf, Of[i][jd], 0, 0, 0);
      }
    }
  }

  // ---- epilogue: normalize, bf16 store to [b][s][h*128+d] ----
#pragma unroll
  for (int i = 0; i < 2; ++i)
#pragma unroll
    for (int r = 0; r < 4; ++r) {
      const int q = q0 + 32 * w + 16 * i + q4 * 4 + r;
      const float inv = 1.f / lI[i * 4 + r];
      ushort* dst = ob + ((size_t)b * S_ + q) * H_ + h * HD_;
#pragma unroll
      for (int jd = 0; jd < 8; ++jd)
        dst[16 * jd + c0] = f2bf(Of[i][jd][r] * inv);
    }
}

// ---------------------------------------------------------------------------
extern "C" void kernel_launch(void* const* d_in, const int* in_sizes, int n_in,
                              void* d_out, int out_size, void* d_ws, size_t ws_size,
                              hipStream_t stream)
{
  const float* hs   = (const float*)d_in[0];
  const float* wqkv = (const float*)d_in[1];
  const float* wo   = (const float*)d_in[2];
  const float* qln  = (const float*)d_in[3];
  const float* kln  = (const float*)d_in[4];
  const int*   pos  = (const int*)d_in[5];

  ushort* ws    = (ushort*)d_ws;
  ushort* hsb   = ws;                       //  8,388,608
  ushort* wqkvb = hsb + 8388608;            // 12,582,912
  ushort* wob   = wqkvb + 12582912;         //  4,194,304
  ushort* qbuf  = wob + 4194304;            //  8,388,608  [b,h,s,d]
  ushort* kbuf  = qbuf + 8388608;           //  8,388,608  [b,h,s,d]
  ushort* vt    = kbuf + 8388608;           //  8,388,608  [b,h,d,s]
  ushort* atb   = vt + 8388608;             //  8,388,608  [b,s,h*d]
  float*  ct    = (float*)(atb + 8388608);  //  262,144
  float*  st    = ct + 262144;              //  262,144   (~119.5 MB total)

  cvt_kernel<<<8192, 256, 0, stream>>>(hs, hsb, 2097152);
  cvt_kernel<<<12288, 256, 0, stream>>>(wqkv, wqkvb, 3145728);
  cvt_kernel<<<4096, 256, 0, stream>>>(wo, wob, 1048576);
  rope_tab<<<1024, 256, 0, stream>>>(pos, ct, st);

  // QKV projection + fused RoPE/RMSNorm/bf16 + transposed V
  gemm_bt<1><<<dim3(TH_ / 128, M_ / 128), 256, 0, stream>>>(
      hsb, wqkvb, nullptr, TH_, H_, qln, kln, ct, st, qbuf, kbuf, vt);

  // flash attention
  attn_mfma<<<dim3(S_ / 128, NH_, 2), 256, 0, stream>>>(qbuf, kbuf, vt, atb);

  // output projection -> fp32 d_out
  gemm_bt<0><<<dim3(H_ / 128, M_ / 128), 256, 0, stream>>>(
      atb, wob, (float*)d_out, H_, H_, nullptr, nullptr, nullptr, nullptr,
      nullptr, nullptr, nullptr);
}

// Round 10
// 422.703 us; speedup vs baseline: 8.0573x; 1.0844x over previous
//
#include <hip/hip_runtime.h>
#include <math.h>

#define S_   2048
#define H_   2048
#define NH_  16
#define HD_  128
#define M_   4096
#define TH_  6144

typedef __attribute__((ext_vector_type(8))) short bf16x8;
typedef __attribute__((ext_vector_type(4))) float f32x4;

__device__ __forceinline__ ushort f2bf(float x) {
  unsigned u = __float_as_uint(x);
  u = (u + 0x7FFFu + ((u >> 16) & 1u)) >> 16;
  return (ushort)u;
}

__device__ __forceinline__ void gll16(const void* g, void* l) {
  __builtin_amdgcn_global_load_lds(
      (const __attribute__((address_space(1))) void*)g,
      (__attribute__((address_space(3))) void*)l, 16, 0, 0);
}

// ---------------------------------------------------------------------------
__global__ void cvt_kernel(const float* __restrict__ src,
                           ushort* __restrict__ dst, int n4) {
  int i = blockIdx.x * blockDim.x + threadIdx.x;
  if (i < n4) {
    float4 v = ((const float4*)src)[i];
    ushort4 o;
    o.x = f2bf(v.x); o.y = f2bf(v.y); o.z = f2bf(v.z); o.w = f2bf(v.w);
    ((ushort4*)dst)[i] = o;
  }
}

// cos/sin tables: ct/st[m*64 + d], d = frequency index 0..63
__global__ void rope_tab(const int* __restrict__ pos,
                         float* __restrict__ ct, float* __restrict__ st) {
  int idx = blockIdx.x * blockDim.x + threadIdx.x;   // < 4096*64
  int m = idx >> 6, d = idx & 63;
  // inv_freq = 10000^(-d/64) = exp2(-d * log2(10000)/64)
  float invf = exp2f(-(float)d * 0.20762050593046020f);
  float ang = (float)pos[m] * invf;
  float s, c;
  sincosf(ang, &s, &c);
  ct[idx] = c;
  st[idx] = s;
}

// ---------------------------------------------------------------------------
// C[M][N] = A[M][K] * Bm[N][K]^T, bf16 inputs, fp32 accum (m97 structure).
// 256 thr = 4 waves; tile 128x128, BK=32; wave w owns rows [32w,32w+32) x all
// 128 cols (2 m-frags x 8 n-frags of 16x16x32 MFMA).
// EPI=0: plain f32 store to C.
// EPI=1: qkv fusion. blockIdx.x>>4: 0=q,1=k (RoPE+RMSNorm -> bf16 [b,h,s,d]),
//        2=v (bf16 transposed store Vt[b,h,d,s]).
// ---------------------------------------------------------------------------
template <int EPI>
__global__ __launch_bounds__(256, 2) void gemm_bt(
    const ushort* __restrict__ A, const ushort* __restrict__ Bm,
    float* __restrict__ C, int Ndim, int Kdim,
    const float* __restrict__ qln, const float* __restrict__ kln,
    const float* __restrict__ ct, const float* __restrict__ st,
    ushort* __restrict__ qbuf, ushort* __restrict__ kbuf,
    ushort* __restrict__ vt)
{
  __shared__ ushort As[128 * 32];
  __shared__ ushort Bs[128 * 32];
  const int t = threadIdx.x, l = t & 63, w = t >> 6;
  const int q4 = l >> 4, c0 = l & 15;
  const int m0 = blockIdx.y * 128, n0 = blockIdx.x * 128;

  // staging: wave w loads A/B rows [32w,32w+32), 1KB chunks of 16 rows
  const ushort* ga0 = A  + (size_t)(m0 + 32 * w + (l >> 2)) * Kdim + (l & 3) * 8;
  const ushort* ga1 = ga0 + (size_t)16 * Kdim;
  const ushort* gb0 = Bm + (size_t)(n0 + 32 * w + (l >> 2)) * Kdim + (l & 3) * 8;
  const ushort* gb1 = gb0 + (size_t)16 * Kdim;
  ushort* lA0 = As + (32 * w) * 32;
  ushort* lA1 = As + (32 * w + 16) * 32;
  ushort* lB0 = Bs + (32 * w) * 32;
  ushort* lB1 = Bs + (32 * w + 16) * 32;

  f32x4 acc[2][8];
#pragma unroll
  for (int i = 0; i < 2; ++i)
#pragma unroll
    for (int j = 0; j < 8; ++j) acc[i][j] = (f32x4){0.f, 0.f, 0.f, 0.f};

  for (int k0 = 0; k0 < Kdim; k0 += 32) {
    gll16(ga0 + k0, lA0);
    gll16(ga1 + k0, lA1);
    gll16(gb0 + k0, lB0);
    gll16(gb1 + k0, lB1);
    __syncthreads();   // loads complete (vmcnt drain at barrier)
    bf16x8 af[2], bfr[8];
#pragma unroll
    for (int i = 0; i < 2; ++i)
      af[i] = *(const bf16x8*)(As + (32 * w + 16 * i + c0) * 32 + q4 * 8);
#pragma unroll
    for (int j = 0; j < 8; ++j)
      bfr[j] = *(const bf16x8*)(Bs + (16 * j + c0) * 32 + q4 * 8);
#pragma unroll
    for (int i = 0; i < 2; ++i)
#pragma unroll
      for (int j = 0; j < 8; ++j)
        acc[i][j] = __builtin_amdgcn_mfma_f32_16x16x32_bf16(
            af[i], bfr[j], acc[i][j], 0, 0, 0);
    __syncthreads();   // frag reads done before next stage overwrites
  }

  if (EPI == 0) {
#pragma unroll
    for (int i = 0; i < 2; ++i)
#pragma unroll
      for (int j = 0; j < 8; ++j) {
        float* cp = C + (size_t)(m0 + 32 * w + 16 * i + q4 * 4) * Ndim
                      + n0 + 16 * j + c0;
#pragma unroll
        for (int r = 0; r < 4; ++r) cp[(size_t)r * Ndim] = acc[i][j][r];
      }
  } else {
    const int seg = blockIdx.x >> 4;   // 0=q, 1=k, 2=v (tile == one head)
    const int h = blockIdx.x & 15;
    if (seg < 2) {
      const float* lnw = (seg == 0) ? qln : kln;
      ushort* obuf = (seg == 0) ? qbuf : kbuf;
      float wl[8];
#pragma unroll
      for (int j = 0; j < 8; ++j) wl[j] = lnw[16 * j + c0];
#pragma unroll
      for (int i = 0; i < 2; ++i)
#pragma unroll
        for (int r = 0; r < 4; ++r) {
          const int m = m0 + 32 * w + 16 * i + q4 * 4 + r;
          const int b = m >> 11, s = m & 2047;
          float y[8], ss = 0.f;
#pragma unroll
          for (int j = 0; j < 4; ++j) {
            const int d = 16 * j + c0;              // freq index 0..63
            const float cs = ct[m * 64 + d], sn = st[m * 64 + d];
            const float x1 = acc[i][j][r], x2 = acc[i][j + 4][r];
            y[j]     = x1 * cs - x2 * sn;
            y[j + 4] = x2 * cs + x1 * sn;
          }
#pragma unroll
          for (int j = 0; j < 8; ++j) ss += y[j] * y[j];
          ss += __shfl_xor(ss, 1, 16);
          ss += __shfl_xor(ss, 2, 16);
          ss += __shfl_xor(ss, 4, 16);
          ss += __shfl_xor(ss, 8, 16);              // full 128-col row sum
          const float sc = rsqrtf(ss * (1.f / 128.f) + 1e-6f);
          ushort* dst = obuf + ((size_t)(b * NH_ + h) * S_ + s) * HD_;
#pragma unroll
          for (int j = 0; j < 8; ++j) dst[16 * j + c0] = f2bf(y[j] * wl[j] * sc);
        }
    } else {
      // V: transposed store Vt[b][h][d][s]
      const int b = m0 >> 11;
      const int s0 = (m0 & 2047) + 32 * w + q4 * 4;
#pragma unroll
      for (int i = 0; i < 2; ++i)
#pragma unroll
        for (int j = 0; j < 8; ++j) {
          const int d = 16 * j + c0;
          const int s = s0 + 16 * i;
          ushort4 o;
          o.x = f2bf(acc[i][j][0]); o.y = f2bf(acc[i][j][1]);
          o.z = f2bf(acc[i][j][2]); o.w = f2bf(acc[i][j][3]);
          *(ushort4*)(vt + ((size_t)(b * NH_ + h) * HD_ + d) * S_ + s) = o;
        }
    }
  }
}

// ---------------------------------------------------------------------------
// Flash attention, bf16 MFMA. Block = 256 thr = 4 waves = 128 q-rows.
// Wave w: q rows [q0+32w, +32). Q in registers. KV tiles of 64 staged into
// XOR-swizzled LDS via pre-swizzled global_load_lds source (G4 fix).
// P goes through swizzled LDS (bf16) for the PV A-operand.
//
// STATIC-MAX SOFTMAX: q,k are RMSNorm'd (unit weights) -> |score*scale| <=
// sqrt(128) < 12 guaranteed. p = exp(s*scale - 12) with fixed shift: no
// running max, no O-rescale, no per-iter shuffles; l reduced once at end.
// ---------------------------------------------------------------------------
__global__ __launch_bounds__(256, 2) void attn_mfma(
    const ushort* __restrict__ qb, const ushort* __restrict__ kb,
    const ushort* __restrict__ vtb, ushort* __restrict__ ob)
{
  __shared__ ushort Ks[64 * 128];   // [kv][d], 16B slot s phys = s^(row&7)
  __shared__ ushort Vs[128 * 64];   // [d][kv], same swizzle
  __shared__ ushort Ps[128 * 64];   // [q][kv], same swizzle
  const int t = threadIdx.x, l = t & 63, w = t >> 6;
  const int q4 = l >> 4, c0 = l & 15;
  const int q0 = blockIdx.x * 128, h = blockIdx.y, b = blockIdx.z;
  const ushort* qh = qb + (size_t)(b * NH_ + h) * S_ * HD_;
  const ushort* kh = kb + (size_t)(b * NH_ + h) * S_ * HD_;
  const ushort* vh = vtb + (size_t)(b * NH_ + h) * HD_ * S_;

  // Q fragments in registers: rows 32w+16i+c0, k-chunk kc (8 elems each)
  bf16x8 qf[2][4];
#pragma unroll
  for (int i = 0; i < 2; ++i)
#pragma unroll
    for (int kc = 0; kc < 4; ++kc)
      qf[i][kc] = *(const bf16x8*)(qh + (size_t)(q0 + 32 * w + 16 * i + c0) * HD_
                                   + kc * 32 + q4 * 8);

  f32x4 Of[2][8];
#pragma unroll
  for (int i = 0; i < 2; ++i)
#pragma unroll
    for (int j = 0; j < 8; ++j) Of[i][j] = (f32x4){0.f, 0.f, 0.f, 0.f};
  float lI[8];
#pragma unroll
  for (int i = 0; i < 8; ++i) lI[i] = 0.f;

  const float scale = 0.08838834764831843f;   // 1/sqrt(128)

  for (int kv0 = 0; kv0 < S_; kv0 += 64) {
    __syncthreads();   // prior iteration's LDS reads complete
#pragma unroll
    for (int j2 = 0; j2 < 4; ++j2) {
      {  // K: chunk = 4 rows x 256B; wave w covers rows [16w,16w+16)
        const int rowK = 16 * w + 4 * j2 + q4;
        gll16(kh + (size_t)(kv0 + rowK) * HD_ + (c0 ^ (rowK & 7)) * 8,
              Ks + (16 * w + 4 * j2) * 128);
      }
      {  // V: chunk = 8 rows x 128B; wave w covers d-rows [32w,32w+32)
        const int rowV = 32 * w + 8 * j2 + (l >> 3);
        gll16(vh + (size_t)rowV * S_ + kv0 + (((l & 7) ^ (rowV & 7)) * 8),
              Vs + (32 * w + 8 * j2) * 64);
      }
    }
    __syncthreads();   // staged tiles visible

    // ---- S = Q K^T : 2x4 frags per wave ----
    f32x4 Sv[2][4];
#pragma unroll
    for (int i = 0; i < 2; ++i)
#pragma unroll
      for (int j = 0; j < 4; ++j) Sv[i][j] = (f32x4){0.f, 0.f, 0.f, 0.f};
#pragma unroll
    for (int kc = 0; kc < 4; ++kc) {
      bf16x8 kf[4];
#pragma unroll
      for (int j = 0; j < 4; ++j) {
        const int row = 16 * j + c0;
        kf[j] = *(const bf16x8*)(Ks + row * 128 + (((kc * 4 + q4) ^ (row & 7)) * 8));
      }
#pragma unroll
      for (int i = 0; i < 2; ++i)
#pragma unroll
        for (int j = 0; j < 4; ++j)
          Sv[i][j] = __builtin_amdgcn_mfma_f32_16x16x32_bf16(
              qf[i][kc], kf[j], Sv[i][j], 0, 0, 0);
    }

    // ---- static-max softmax: p = exp(s*scale - 12); P -> swizzled LDS ----
#pragma unroll
    for (int i = 0; i < 2; ++i)
#pragma unroll
      for (int r = 0; r < 4; ++r) {
        const int idx = i * 4 + r;
        const float p0 = __expf(__builtin_fmaf(Sv[i][0][r], scale, -12.0f));
        const float p1 = __expf(__builtin_fmaf(Sv[i][1][r], scale, -12.0f));
        const float p2 = __expf(__builtin_fmaf(Sv[i][2][r], scale, -12.0f));
        const float p3 = __expf(__builtin_fmaf(Sv[i][3][r], scale, -12.0f));
        lI[idx] += (p0 + p1) + (p2 + p3);
        const int qrow = 32 * w + 16 * i + q4 * 4 + r;
        const int x = qrow & 7, cb = c0 & 7, ch = c0 >> 3;
        Ps[qrow * 64 + ((0 + ch) ^ x) * 8 + cb] = f2bf(p0);  // col 16*0+c0
        Ps[qrow * 64 + ((2 + ch) ^ x) * 8 + cb] = f2bf(p1);  // col 16*1+c0
        Ps[qrow * 64 + ((4 + ch) ^ x) * 8 + cb] = f2bf(p2);  // col 16*2+c0
        Ps[qrow * 64 + ((6 + ch) ^ x) * 8 + cb] = f2bf(p3);  // col 16*3+c0
      }

    // ---- O += P V  (Ps written & read by the same wave; DS in-order) ----
#pragma unroll
    for (int kc2 = 0; kc2 < 2; ++kc2) {
      bf16x8 pa[2];
#pragma unroll
      for (int i = 0; i < 2; ++i) {
        const int row = 32 * w + 16 * i + c0;
        pa[i] = *(const bf16x8*)(Ps + row * 64 + (((kc2 * 4 + q4) ^ (row & 7)) * 8));
      }
#pragma unroll
      for (int jd = 0; jd < 8; ++jd) {
        const int row = 16 * jd + c0;
        const bf16x8 vf =
            *(const bf16x8*)(Vs + row * 64 + (((kc2 * 4 + q4) ^ (row & 7)) * 8));
#pragma unroll
        for (int i = 0; i < 2; ++i)
          Of[i][jd] = __builtin_amdgcn_mfma_f32_16x16x32_bf16(
              pa[i], vf, Of[i][jd], 0, 0, 0);
      }
    }
  }

  // ---- deferred l reduction over the 16 kv-column lanes (once, not per-iter)
#pragma unroll
  for (int idx = 0; idx < 8; ++idx) {
    lI[idx] += __shfl_xor(lI[idx], 1, 16);
    lI[idx] += __shfl_xor(lI[idx], 2, 16);
    lI[idx] += __shfl_xor(lI[idx], 4, 16);
    lI[idx] += __shfl_xor(lI[idx], 8, 16);
  }

  // ---- epilogue: normalize, bf16 store to [b][s][h*128+d] ----
#pragma unroll
  for (int i = 0; i < 2; ++i)
#pragma unroll
    for (int r = 0; r < 4; ++r) {
      const int q = q0 + 32 * w + 16 * i + q4 * 4 + r;
      const float inv = 1.f / lI[i * 4 + r];
      ushort* dst = ob + ((size_t)b * S_ + q) * H_ + h * HD_;
#pragma unroll
      for (int jd = 0; jd < 8; ++jd)
        dst[16 * jd + c0] = f2bf(Of[i][jd][r] * inv);
    }
}

// ---------------------------------------------------------------------------
extern "C" void kernel_launch(void* const* d_in, const int* in_sizes, int n_in,
                              void* d_out, int out_size, void* d_ws, size_t ws_size,
                              hipStream_t stream)
{
  const float* hs   = (const float*)d_in[0];
  const float* wqkv = (const float*)d_in[1];
  const float* wo   = (const float*)d_in[2];
  const float* qln  = (const float*)d_in[3];
  const float* kln  = (const float*)d_in[4];
  const int*   pos  = (const int*)d_in[5];

  ushort* ws    = (ushort*)d_ws;
  ushort* hsb   = ws;                       //  8,388,608
  ushort* wqkvb = hsb + 8388608;            // 12,582,912
  ushort* wob   = wqkvb + 12582912;         //  4,194,304
  ushort* qbuf  = wob + 4194304;            //  8,388,608  [b,h,s,d]
  ushort* kbuf  = qbuf + 8388608;           //  8,388,608  [b,h,s,d]
  ushort* vt    = kbuf + 8388608;           //  8,388,608  [b,h,d,s]
  ushort* atb   = vt + 8388608;             //  8,388,608  [b,s,h*d]
  float*  ct    = (float*)(atb + 8388608);  //  262,144
  float*  st    = ct + 262144;              //  262,144   (~119.5 MB total)

  cvt_kernel<<<8192, 256, 0, stream>>>(hs, hsb, 2097152);
  cvt_kernel<<<12288, 256, 0, stream>>>(wqkv, wqkvb, 3145728);
  cvt_kernel<<<4096, 256, 0, stream>>>(wo, wob, 1048576);
  rope_tab<<<1024, 256, 0, stream>>>(pos, ct, st);

  // QKV projection + fused RoPE/RMSNorm/bf16 + transposed V
  gemm_bt<1><<<dim3(TH_ / 128, M_ / 128), 256, 0, stream>>>(
      hsb, wqkvb, nullptr, TH_, H_, qln, kln, ct, st, qbuf, kbuf, vt);

  // flash attention
  attn_mfma<<<dim3(S_ / 128, NH_, 2), 256, 0, stream>>>(qbuf, kbuf, vt, atb);

  // output projection -> fp32 d_out
  gemm_bt<0><<<dim3(H_ / 128, M_ / 128), 256, 0, stream>>>(
      atb, wob, (float*)d_out, H_, H_, nullptr, nullptr, nullptr, nullptr,
      nullptr, nullptr, nullptr);
}

// Round 11
// 411.672 us; speedup vs baseline: 8.2732x; 1.0268x over previous
//
#include <hip/hip_runtime.h>
#include <math.h>

#define S_   2048
#define H_   2048
#define NH_  16
#define HD_  128
#define M_   4096
#define TH_  6144

typedef __attribute__((ext_vector_type(8))) short bf16x8;
typedef __attribute__((ext_vector_type(4))) float f32x4;

__device__ __forceinline__ ushort f2bf(float x) {
  unsigned u = __float_as_uint(x);
  u = (u + 0x7FFFu + ((u >> 16) & 1u)) >> 16;
  return (ushort)u;
}

__device__ __forceinline__ void gll16(const void* g, void* l) {
  __builtin_amdgcn_global_load_lds(
      (const __attribute__((address_space(1))) void*)g,
      (__attribute__((address_space(3))) void*)l, 16, 0, 0);
}

// ---------------------------------------------------------------------------
__global__ void cvt_kernel(const float* __restrict__ src,
                           ushort* __restrict__ dst, int n4) {
  int i = blockIdx.x * blockDim.x + threadIdx.x;
  if (i < n4) {
    float4 v = ((const float4*)src)[i];
    ushort4 o;
    o.x = f2bf(v.x); o.y = f2bf(v.y); o.z = f2bf(v.z); o.w = f2bf(v.w);
    ((ushort4*)dst)[i] = o;
  }
}

// cos/sin tables: ct/st[m*64 + d], d = frequency index 0..63
__global__ void rope_tab(const int* __restrict__ pos,
                         float* __restrict__ ct, float* __restrict__ st) {
  int idx = blockIdx.x * blockDim.x + threadIdx.x;   // < 4096*64
  int m = idx >> 6, d = idx & 63;
  // inv_freq = 10000^(-d/64) = exp2(-d * log2(10000)/64)
  float invf = exp2f(-(float)d * 0.20762050593046020f);
  float ang = (float)pos[m] * invf;
  float s, c;
  sincosf(ang, &s, &c);
  ct[idx] = c;
  st[idx] = s;
}

// ---------------------------------------------------------------------------
// C[M][N] = A[M][K] * Bm[N][K]^T, bf16 inputs, fp32 accum (m97 structure).
// 256 thr = 4 waves; tile 128x128, BK=32; wave w owns rows [32w,32w+32) x all
// 128 cols (2 m-frags x 8 n-frags of 16x16x32 MFMA).
// EPI=0: plain f32 store to C.
// EPI=1: qkv fusion. blockIdx.x>>4: 0=q,1=k (RoPE+RMSNorm -> bf16 [b,h,s,d]),
//        2=v (bf16 transposed store Vt[b,h,d,s]).
// ---------------------------------------------------------------------------
template <int EPI>
__global__ __launch_bounds__(256, 2) void gemm_bt(
    const ushort* __restrict__ A, const ushort* __restrict__ Bm,
    float* __restrict__ C, int Ndim, int Kdim,
    const float* __restrict__ qln, const float* __restrict__ kln,
    const float* __restrict__ ct, const float* __restrict__ st,
    ushort* __restrict__ qbuf, ushort* __restrict__ kbuf,
    ushort* __restrict__ vt)
{
  __shared__ ushort As[128 * 32];
  __shared__ ushort Bs[128 * 32];
  const int t = threadIdx.x, l = t & 63, w = t >> 6;
  const int q4 = l >> 4, c0 = l & 15;
  const int m0 = blockIdx.y * 128, n0 = blockIdx.x * 128;

  // staging: wave w loads A/B rows [32w,32w+32), 1KB chunks of 16 rows
  const ushort* ga0 = A  + (size_t)(m0 + 32 * w + (l >> 2)) * Kdim + (l & 3) * 8;
  const ushort* ga1 = ga0 + (size_t)16 * Kdim;
  const ushort* gb0 = Bm + (size_t)(n0 + 32 * w + (l >> 2)) * Kdim + (l & 3) * 8;
  const ushort* gb1 = gb0 + (size_t)16 * Kdim;
  ushort* lA0 = As + (32 * w) * 32;
  ushort* lA1 = As + (32 * w + 16) * 32;
  ushort* lB0 = Bs + (32 * w) * 32;
  ushort* lB1 = Bs + (32 * w + 16) * 32;

  f32x4 acc[2][8];
#pragma unroll
  for (int i = 0; i < 2; ++i)
#pragma unroll
    for (int j = 0; j < 8; ++j) acc[i][j] = (f32x4){0.f, 0.f, 0.f, 0.f};

  for (int k0 = 0; k0 < Kdim; k0 += 32) {
    gll16(ga0 + k0, lA0);
    gll16(ga1 + k0, lA1);
    gll16(gb0 + k0, lB0);
    gll16(gb1 + k0, lB1);
    __syncthreads();   // loads complete (vmcnt drain at barrier)
    bf16x8 af[2], bfr[8];
#pragma unroll
    for (int i = 0; i < 2; ++i)
      af[i] = *(const bf16x8*)(As + (32 * w + 16 * i + c0) * 32 + q4 * 8);
#pragma unroll
    for (int j = 0; j < 8; ++j)
      bfr[j] = *(const bf16x8*)(Bs + (16 * j + c0) * 32 + q4 * 8);
#pragma unroll
    for (int i = 0; i < 2; ++i)
#pragma unroll
      for (int j = 0; j < 8; ++j)
        acc[i][j] = __builtin_amdgcn_mfma_f32_16x16x32_bf16(
            af[i], bfr[j], acc[i][j], 0, 0, 0);
    __syncthreads();   // frag reads done before next stage overwrites
  }

  if (EPI == 0) {
#pragma unroll
    for (int i = 0; i < 2; ++i)
#pragma unroll
      for (int j = 0; j < 8; ++j) {
        float* cp = C + (size_t)(m0 + 32 * w + 16 * i + q4 * 4) * Ndim
                      + n0 + 16 * j + c0;
#pragma unroll
        for (int r = 0; r < 4; ++r) cp[(size_t)r * Ndim] = acc[i][j][r];
      }
  } else {
    const int seg = blockIdx.x >> 4;   // 0=q, 1=k, 2=v (tile == one head)
    const int h = blockIdx.x & 15;
    if (seg < 2) {
      const float* lnw = (seg == 0) ? qln : kln;
      ushort* obuf = (seg == 0) ? qbuf : kbuf;
      float wl[8];
#pragma unroll
      for (int j = 0; j < 8; ++j) wl[j] = lnw[16 * j + c0];
#pragma unroll
      for (int i = 0; i < 2; ++i)
#pragma unroll
        for (int r = 0; r < 4; ++r) {
          const int m = m0 + 32 * w + 16 * i + q4 * 4 + r;
          const int b = m >> 11, s = m & 2047;
          float y[8], ss = 0.f;
#pragma unroll
          for (int j = 0; j < 4; ++j) {
            const int d = 16 * j + c0;              // freq index 0..63
            const float cs = ct[m * 64 + d], sn = st[m * 64 + d];
            const float x1 = acc[i][j][r], x2 = acc[i][j + 4][r];
            y[j]     = x1 * cs - x2 * sn;
            y[j + 4] = x2 * cs + x1 * sn;
          }
#pragma unroll
          for (int j = 0; j < 8; ++j) ss += y[j] * y[j];
          ss += __shfl_xor(ss, 1, 16);
          ss += __shfl_xor(ss, 2, 16);
          ss += __shfl_xor(ss, 4, 16);
          ss += __shfl_xor(ss, 8, 16);              // full 128-col row sum
          const float sc = rsqrtf(ss * (1.f / 128.f) + 1e-6f);
          ushort* dst = obuf + ((size_t)(b * NH_ + h) * S_ + s) * HD_;
#pragma unroll
          for (int j = 0; j < 8; ++j) dst[16 * j + c0] = f2bf(y[j] * wl[j] * sc);
        }
    } else {
      // V: transposed store Vt[b][h][d][s]
      const int b = m0 >> 11;
      const int s0 = (m0 & 2047) + 32 * w + q4 * 4;
#pragma unroll
      for (int i = 0; i < 2; ++i)
#pragma unroll
        for (int j = 0; j < 8; ++j) {
          const int d = 16 * j + c0;
          const int s = s0 + 16 * i;
          ushort4 o;
          o.x = f2bf(acc[i][j][0]); o.y = f2bf(acc[i][j][1]);
          o.z = f2bf(acc[i][j][2]); o.w = f2bf(acc[i][j][3]);
          *(ushort4*)(vt + ((size_t)(b * NH_ + h) * HD_ + d) * S_ + s) = o;
        }
    }
  }
}

// ---------------------------------------------------------------------------
// Flash attention, bf16 MFMA. Block = 256 thr = 4 waves = 128 q-rows.
// Wave w: q rows [q0+32w, +32). Q in registers. KV tiles of 64 staged into
// XOR-swizzled LDS via pre-swizzled global_load_lds source (G4 fix).
// P goes through swizzled LDS (bf16) for the PV A-operand.
//
// STATIC-MAX SOFTMAX: q,k unit-RMS -> |score*scale| < 12; fixed shift -12.
// 2-PHASE PREFETCH (T3-minimum): K/V double-buffered; STAGE(buf^1, t+1)
// issued BEFORE compute(buf); single vmcnt-drain barrier per iter. Load
// latency hides under QK^T+softmax+PV of the current tile.
// ---------------------------------------------------------------------------
__global__ __launch_bounds__(256, 2) void attn_mfma(
    const ushort* __restrict__ qb, const ushort* __restrict__ kb,
    const ushort* __restrict__ vtb, ushort* __restrict__ ob)
{
  __shared__ ushort Ks[2][64 * 128];   // [kv][d], 16B slot s phys = s^(row&7)
  __shared__ ushort Vs[2][128 * 64];   // [d][kv], same swizzle
  __shared__ ushort Ps[128 * 64];      // [q][kv], same swizzle (wave-private)
  const int t = threadIdx.x, l = t & 63, w = t >> 6;
  const int q4 = l >> 4, c0 = l & 15;
  const int q0 = blockIdx.x * 128, h = blockIdx.y, b = blockIdx.z;
  const ushort* qh = qb + (size_t)(b * NH_ + h) * S_ * HD_;
  const ushort* kh = kb + (size_t)(b * NH_ + h) * S_ * HD_;
  const ushort* vh = vtb + (size_t)(b * NH_ + h) * HD_ * S_;

  // Q fragments in registers: rows 32w+16i+c0, k-chunk kc (8 elems each)
  bf16x8 qf[2][4];
#pragma unroll
  for (int i = 0; i < 2; ++i)
#pragma unroll
    for (int kc = 0; kc < 4; ++kc)
      qf[i][kc] = *(const bf16x8*)(qh + (size_t)(q0 + 32 * w + 16 * i + c0) * HD_
                                   + kc * 32 + q4 * 8);

  f32x4 Of[2][8];
#pragma unroll
  for (int i = 0; i < 2; ++i)
#pragma unroll
    for (int j = 0; j < 8; ++j) Of[i][j] = (f32x4){0.f, 0.f, 0.f, 0.f};
  float lI[8];
#pragma unroll
  for (int i = 0; i < 8; ++i) lI[i] = 0.f;

  const float scale = 0.08838834764831843f;   // 1/sqrt(128)

  // issue the 8 global_load_lds for K/V tile kv0 into buffer `buf`
  auto STAGE = [&](int buf, int kv0) {
#pragma unroll
    for (int j2 = 0; j2 < 4; ++j2) {
      const int rowK = 16 * w + 4 * j2 + q4;
      gll16(kh + (size_t)(kv0 + rowK) * HD_ + (c0 ^ (rowK & 7)) * 8,
            &Ks[buf][(16 * w + 4 * j2) * 128]);
      const int rowV = 32 * w + 8 * j2 + (l >> 3);
      gll16(vh + (size_t)rowV * S_ + kv0 + (((l & 7) ^ (rowV & 7)) * 8),
            &Vs[buf][(32 * w + 8 * j2) * 64]);
    }
  };

  // QK^T + static-max softmax + PV on buffer `buf`
  auto COMPUTE = [&](int buf) {
    f32x4 Sv[2][4];
#pragma unroll
    for (int i = 0; i < 2; ++i)
#pragma unroll
      for (int j = 0; j < 4; ++j) Sv[i][j] = (f32x4){0.f, 0.f, 0.f, 0.f};
#pragma unroll
    for (int kc = 0; kc < 4; ++kc) {
      bf16x8 kf[4];
#pragma unroll
      for (int j = 0; j < 4; ++j) {
        const int row = 16 * j + c0;
        kf[j] = *(const bf16x8*)(&Ks[buf][row * 128 +
                                          (((kc * 4 + q4) ^ (row & 7)) * 8)]);
      }
#pragma unroll
      for (int i = 0; i < 2; ++i)
#pragma unroll
        for (int j = 0; j < 4; ++j)
          Sv[i][j] = __builtin_amdgcn_mfma_f32_16x16x32_bf16(
              qf[i][kc], kf[j], Sv[i][j], 0, 0, 0);
    }

#pragma unroll
    for (int i = 0; i < 2; ++i)
#pragma unroll
      for (int r = 0; r < 4; ++r) {
        const int idx = i * 4 + r;
        const float p0 = __expf(__builtin_fmaf(Sv[i][0][r], scale, -12.0f));
        const float p1 = __expf(__builtin_fmaf(Sv[i][1][r], scale, -12.0f));
        const float p2 = __expf(__builtin_fmaf(Sv[i][2][r], scale, -12.0f));
        const float p3 = __expf(__builtin_fmaf(Sv[i][3][r], scale, -12.0f));
        lI[idx] += (p0 + p1) + (p2 + p3);
        const int qrow = 32 * w + 16 * i + q4 * 4 + r;
        const int x = qrow & 7, cb = c0 & 7, ch = c0 >> 3;
        Ps[qrow * 64 + ((0 + ch) ^ x) * 8 + cb] = f2bf(p0);  // col 16*0+c0
        Ps[qrow * 64 + ((2 + ch) ^ x) * 8 + cb] = f2bf(p1);  // col 16*1+c0
        Ps[qrow * 64 + ((4 + ch) ^ x) * 8 + cb] = f2bf(p2);  // col 16*2+c0
        Ps[qrow * 64 + ((6 + ch) ^ x) * 8 + cb] = f2bf(p3);  // col 16*3+c0
      }

#pragma unroll
    for (int kc2 = 0; kc2 < 2; ++kc2) {
      bf16x8 pa[2];
#pragma unroll
      for (int i = 0; i < 2; ++i) {
        const int row = 32 * w + 16 * i + c0;
        pa[i] = *(const bf16x8*)(Ps + row * 64 +
                                 (((kc2 * 4 + q4) ^ (row & 7)) * 8));
      }
#pragma unroll
      for (int jd = 0; jd < 8; ++jd) {
        const int row = 16 * jd + c0;
        const bf16x8 vf = *(const bf16x8*)(&Vs[buf][row * 64 +
                                   (((kc2 * 4 + q4) ^ (row & 7)) * 8)]);
#pragma unroll
        for (int i = 0; i < 2; ++i)
          Of[i][jd] = __builtin_amdgcn_mfma_f32_16x16x32_bf16(
              pa[i], vf, Of[i][jd], 0, 0, 0);
      }
    }
  };

  STAGE(0, 0);
  __syncthreads();   // vmcnt drain at barrier: tile 0 visible

  for (int it = 0; it < S_ / 64; it += 2) {
    // even tile: prefetch next into buf1, compute buf0
    STAGE(1, (it + 1) * 64);
    COMPUTE(0);
    __syncthreads();   // drains prefetch; protects buf0 for reuse at it+2
    // odd tile: prefetch next into buf0 (if any), compute buf1
    if (it + 2 < S_ / 64) STAGE(0, (it + 2) * 64);
    COMPUTE(1);
    __syncthreads();
  }

  // ---- deferred l reduction over the 16 kv-column lanes (once) ----
#pragma unroll
  for (int idx = 0; idx < 8; ++idx) {
    lI[idx] += __shfl_xor(lI[idx], 1, 16);
    lI[idx] += __shfl_xor(lI[idx], 2, 16);
    lI[idx] += __shfl_xor(lI[idx], 4, 16);
    lI[idx] += __shfl_xor(lI[idx], 8, 16);
  }

  // ---- epilogue: normalize, bf16 store to [b][s][h*128+d] ----
#pragma unroll
  for (int i = 0; i < 2; ++i)
#pragma unroll
    for (int r = 0; r < 4; ++r) {
      const int q = q0 + 32 * w + 16 * i + q4 * 4 + r;
      const float inv = 1.f / lI[i * 4 + r];
      ushort* dst = ob + ((size_t)b * S_ + q) * H_ + h * HD_;
#pragma unroll
      for (int jd = 0; jd < 8; ++jd)
        dst[16 * jd + c0] = f2bf(Of[i][jd][r] * inv);
    }
}

// ---------------------------------------------------------------------------
extern "C" void kernel_launch(void* const* d_in, const int* in_sizes, int n_in,
                              void* d_out, int out_size, void* d_ws, size_t ws_size,
                              hipStream_t stream)
{
  const float* hs   = (const float*)d_in[0];
  const float* wqkv = (const float*)d_in[1];
  const float* wo   = (const float*)d_in[2];
  const float* qln  = (const float*)d_in[3];
  const float* kln  = (const float*)d_in[4];
  const int*   pos  = (const int*)d_in[5];

  ushort* ws    = (ushort*)d_ws;
  ushort* hsb   = ws;                       //  8,388,608
  ushort* wqkvb = hsb + 8388608;            // 12,582,912
  ushort* wob   = wqkvb + 12582912;         //  4,194,304
  ushort* qbuf  = wob + 4194304;            //  8,388,608  [b,h,s,d]
  ushort* kbuf  = qbuf + 8388608;           //  8,388,608  [b,h,s,d]
  ushort* vt    = kbuf + 8388608;           //  8,388,608  [b,h,d,s]
  ushort* atb   = vt + 8388608;             //  8,388,608  [b,s,h*d]
  float*  ct    = (float*)(atb + 8388608);  //  262,144
  float*  st    = ct + 262144;              //  262,144   (~119.5 MB total)

  cvt_kernel<<<8192, 256, 0, stream>>>(hs, hsb, 2097152);
  cvt_kernel<<<12288, 256, 0, stream>>>(wqkv, wqkvb, 3145728);
  cvt_kernel<<<4096, 256, 0, stream>>>(wo, wob, 1048576);
  rope_tab<<<1024, 256, 0, stream>>>(pos, ct, st);

  // QKV projection + fused RoPE/RMSNorm/bf16 + transposed V
  gemm_bt<1><<<dim3(TH_ / 128, M_ / 128), 256, 0, stream>>>(
      hsb, wqkvb, nullptr, TH_, H_, qln, kln, ct, st, qbuf, kbuf, vt);

  // flash attention
  attn_mfma<<<dim3(S_ / 128, NH_, 2), 256, 0, stream>>>(qbuf, kbuf, vt, atb);

  // output projection -> fp32 d_out
  gemm_bt<0><<<dim3(H_ / 128, M_ / 128), 256, 0, stream>>>(
      atb, wob, (float*)d_out, H_, H_, nullptr, nullptr, nullptr, nullptr,
      nullptr, nullptr, nullptr);
}